// Round 6
// baseline (66.780 us; speedup 1.0000x reference)
//
#include <hip/hip_runtime.h>
#include <stdint.h>

#define B_ 4
#define C_ 512
#define N_ 4096
#define D_ 64
#define LOG2E 1.4426950408889634f

typedef __attribute__((ext_vector_type(8))) short short8;
typedef __attribute__((ext_vector_type(4))) float f32x4;
typedef __attribute__((ext_vector_type(16))) float f32x16;
typedef unsigned short ushort_t;

static __device__ __forceinline__ ushort_t f2bf(float f) {
    union { float f; uint32_t u; } v; v.f = f;
    uint32_t u = v.u;
    uint32_t r = u + 0x7FFFu + ((u >> 16) & 1u);
    return (ushort_t)(r >> 16);
}
static __device__ __forceinline__ float bf2f(uint32_t u) {
    union { uint32_t u; float f; } v; v.u = u << 16;
    return v.f;
}
static __device__ __forceinline__ uint32_t cvtpk_bf16(float lo, float hi) {
    uint32_t r;
    asm("v_cvt_pk_bf16_f32 %0, %1, %2" : "=v"(r) : "v"(lo), "v"(hi));
    return r;
}
// async global->LDS, 16B per lane. LDS dst must be wave-uniform base + lane*16.
static __device__ __forceinline__ void gl16(const ushort_t* g, ushort_t* l) {
    __builtin_amdgcn_global_load_lds(
        (const __attribute__((address_space(1))) void*)g,
        (__attribute__((address_space(3))) void*)l, 16, 0, 0);
}

// -------------------------------------------------------------------------
// Kernel 1: merged F/G/H projections, 512 threads (verified R5).
// F gets LOG2E folded in; F -> Ftf, H -> Vtf in attn-fragment order.
// -------------------------------------------------------------------------
__global__ __launch_bounds__(512) void proj_fgh(
    const float* __restrict__ x,
    const float* __restrict__ wf, const float* __restrict__ bf,
    const float* __restrict__ wg, const float* __restrict__ bg,
    const float* __restrict__ wh, const float* __restrict__ bh,
    ushort_t* __restrict__ Ftf, ushort_t* __restrict__ Gt,
    ushort_t* __restrict__ Vtf)
{
    const int b    = blockIdx.y;
    const int tile = blockIdx.x;
    const int n0   = tile * 64;
    const int tid  = threadIdx.x;          // 0..511
    const int wv   = tid >> 6;             // 0..7
    const int mw   = wv & 3;
    const int hi   = wv >> 2;
    const int lane = tid & 63;
    const int g    = lane >> 4;
    const int r    = lane & 15;

    __shared__ ushort_t As[64][40];        // [loc][k]
    __shared__ ushort_t Bs[192][40];       // [o][k]

    f32x4 acc[6];
    #pragma unroll
    for (int t = 0; t < 6; ++t) acc[t] = (f32x4){0.f, 0.f, 0.f, 0.f};

    const int ka = tid >> 4;               // 0..31
    const int mb = (tid & 15) * 4;         // 0..60
    const int kb = (tid & 7) * 4;          // 0..28
    const int ow = tid >> 3;               // 0..63

    const float* xp  = x  + ((size_t)b * C_ + ka) * N_ + n0 + mb;
    const float* wp0 = wf + (size_t)ow * C_ + kb;
    const float* wp1 = wg + (size_t)ow * C_ + kb;
    const float* wp2 = wh + (size_t)ow * C_ + kb;

    float4 xa = *(const float4*)xp;
    float4 w0 = *(const float4*)wp0;
    float4 w1 = *(const float4*)wp1;
    float4 w2 = *(const float4*)wp2;

    for (int k0 = 0; k0 < C_; k0 += 32) {
        As[mb + 0][ka] = f2bf(xa.x);
        As[mb + 1][ka] = f2bf(xa.y);
        As[mb + 2][ka] = f2bf(xa.z);
        As[mb + 3][ka] = f2bf(xa.w);
        {
            uint2 p0, p1, p2;
            p0.x = cvtpk_bf16(w0.x, w0.y); p0.y = cvtpk_bf16(w0.z, w0.w);
            p1.x = cvtpk_bf16(w1.x, w1.y); p1.y = cvtpk_bf16(w1.z, w1.w);
            p2.x = cvtpk_bf16(w2.x, w2.y); p2.y = cvtpk_bf16(w2.z, w2.w);
            *(uint2*)&Bs[ow][kb]       = p0;
            *(uint2*)&Bs[64 + ow][kb]  = p1;
            *(uint2*)&Bs[128 + ow][kb] = p2;
        }
        if (k0 + 32 < C_) {
            xa = *(const float4*)(xp + (size_t)(k0 + 32) * N_);
            w0 = *(const float4*)(wp0 + k0 + 32);
            w1 = *(const float4*)(wp1 + k0 + 32);
            w2 = *(const float4*)(wp2 + k0 + 32);
        }
        __syncthreads();
        short8 a = *(const short8*)&As[16 * mw + r][8 * g];
        __builtin_amdgcn_s_setprio(1);
        #pragma unroll
        for (int tt = 0; tt < 6; ++tt) {
            const int T = hi * 6 + tt;
            short8 bbv = *(const short8*)&Bs[T * 16 + r][8 * g];
            acc[tt] = __builtin_amdgcn_mfma_f32_16x16x32_bf16(a, bbv, acc[tt], 0, 0, 0);
        }
        __builtin_amdgcn_s_setprio(0);
        __syncthreads();
    }

    // ---- G: direct store (rows of Gt)
    #pragma unroll
    for (int u = 0; u < 2; ++u) {
        const int tt = hi ? u : (4 + u);
        const int og = hi ? (32 + u * 16 + r) : (u * 16 + r);
        const float bvv = bg[og];
        #pragma unroll
        for (int j = 0; j < 4; ++j) {
            const int loc = n0 + 16 * mw + 4 * g + j;
            Gt[((size_t)b * N_ + loc) * D_ + og] = f2bf(acc[tt][j] + bvv);
        }
    }

    ushort_t (*bb)[72] = (ushort_t(*)[72])Bs;

    // ---- F -> bb -> Ftf (fragment order), LOG2E folded. Waves 0-3 own F.
    if (hi == 0) {
        #pragma unroll
        for (int tt = 0; tt < 4; ++tt) {
            const int o = tt * 16 + r;
            const float bvv = bf[o];
            #pragma unroll
            for (int j = 0; j < 4; ++j)
                bb[16 * mw + 4 * g + j][o] = f2bf((acc[tt][j] + bvv) * LOG2E);
        }
    }
    __syncthreads();
    {
        const int f  = wv;                 // 0..7 = cc*4 + s
        const int cc = f >> 2, s = f & 3;
        short8 v = *(const short8*)&bb[32 * cc + (lane & 31)][16 * s + 8 * (lane >> 5)];
        *(short8*)&Ftf[(((size_t)b * 64 + tile) * 8 + f) * 512 + lane * 8] = v;
    }
    __syncthreads();

    // ---- H -> bb -> Vtf (fragment order). Waves 4-7 own H.
    if (hi == 1) {
        #pragma unroll
        for (int tt = 2; tt < 6; ++tt) {
            const int o = (tt - 2) * 16 + r;
            const float bvv = bh[o];
            #pragma unroll
            for (int j = 0; j < 4; ++j)
                bb[16 * mw + 4 * g + j][o] = f2bf(acc[tt][j] + bvv);
        }
    }
    __syncthreads();
    {
        const int f   = wv;                // cc*4 + sub*2 + dt
        const int cc  = f >> 2, sub = (f >> 1) & 1, dt = f & 1;
        const int h2l = lane >> 5;
        short8 v;
        #pragma unroll
        for (int e = 0; e < 8; ++e) {
            const int i = 32 * cc + 16 * sub + (e & 3) + 8 * (e >> 2) + 4 * h2l;
            v[e] = (short)bb[i][32 * dt + (lane & 31)];
        }
        *(short8*)&Vtf[(((size_t)b * 64 + tile) * 8 + f) * 512 + lane * 8] = v;
    }
}

// -------------------------------------------------------------------------
// Kernel 2: flash attention, 32x32x16 MFMA, split-K, Q=64 PER WAVE.
// Each K/V fragment read now feeds 2 MFMAs (q-blocks A,B) -> LDS-read per
// FLOP halves (was the bottleneck: ~6x oversubscribed LDS pipe).
// Max-free exact softmax (scores bounded), sync->prefetch->compute order.
// -------------------------------------------------------------------------
__global__ __launch_bounds__(256, 2) void attn(
    const ushort_t* __restrict__ Ftf, const ushort_t* __restrict__ Gt,
    const ushort_t* __restrict__ Vtf, ushort_t* __restrict__ Ot,
    ushort_t* __restrict__ Op, float* __restrict__ ml, int ksplit)
{
    const int b    = blockIdx.z;
    const int part = blockIdx.y;
    const int tid  = threadIdx.x;
    const int wave = tid >> 6;
    const int lane = tid & 63;
    const int l31  = lane & 31;
    const int h2   = lane >> 5;
    const int j0   = blockIdx.x * 256 + wave * 64;   // q-block A; B = +32
    const int NT   = (N_ / ksplit) / 64;
    const int kt0  = part * NT;

    __shared__ __align__(16) ushort_t Ks[2][4096];
    __shared__ __align__(16) ushort_t Vs[2][4096];

    const ushort_t* qrowA = Gt + ((size_t)b * N_ + j0 + l31) * D_ + 8 * h2;
    const ushort_t* qrowB = qrowA + (size_t)32 * D_;
    const short8 qA0 = *(const short8*)(qrowA);
    const short8 qA1 = *(const short8*)(qrowA + 16);
    const short8 qA2 = *(const short8*)(qrowA + 32);
    const short8 qA3 = *(const short8*)(qrowA + 48);
    const short8 qB0 = *(const short8*)(qrowB);
    const short8 qB1 = *(const short8*)(qrowB + 16);
    const short8 qB2 = *(const short8*)(qrowB + 32);
    const short8 qB3 = *(const short8*)(qrowB + 48);

    const ushort_t* Kt = Ftf + ((size_t)b * 64 + kt0) * 4096;
    const ushort_t* Vt = Vtf + ((size_t)b * 64 + kt0) * 4096;

    f32x16 oAA, oBA, oAB, oBB;   // o{dhalf}{qblock}
    #pragma unroll
    for (int q = 0; q < 16; ++q) { oAA[q] = 0.f; oBA[q] = 0.f; oAB[q] = 0.f; oBB[q] = 0.f; }
    float lA = 0.f, lB = 0.f;

    // prologue: issue tile 0 DMA -> buf 0
    gl16(Kt + tid * 8,         &Ks[0][tid * 8]);
    gl16(Kt + (tid + 256) * 8, &Ks[0][(tid + 256) * 8]);
    gl16(Vt + tid * 8,         &Vs[0][tid * 8]);
    gl16(Vt + (tid + 256) * 8, &Vs[0][(tid + 256) * 8]);

    int buf = 0;
    for (int t = 0; t < NT; ++t) {
        __syncthreads();   // drains tile-t DMA (issued a full iter ago)
        if (t + 1 < NT) {
            const ushort_t* kg = Kt + (size_t)(t + 1) * 4096;
            const ushort_t* vg = Vt + (size_t)(t + 1) * 4096;
            const int nb = buf ^ 1;
            gl16(kg + tid * 8,         &Ks[nb][tid * 8]);
            gl16(kg + (tid + 256) * 8, &Ks[nb][(tid + 256) * 8]);
            gl16(vg + tid * 8,         &Vs[nb][tid * 8]);
            gl16(vg + (tid + 256) * 8, &Vs[nb][(tid + 256) * 8]);
        }
        #pragma unroll
        for (int cc = 0; cc < 2; ++cc) {
            const ushort_t* kb0 = &Ks[buf][cc * 2048];
            f32x16 sxA, sxB;
            #pragma unroll
            for (int q = 0; q < 16; ++q) { sxA[q] = 0.f; sxB[q] = 0.f; }
            __builtin_amdgcn_s_setprio(1);
            {
                const short8 k0 = *(const short8*)(kb0 + 0 * 512 + lane * 8);
                sxA = __builtin_amdgcn_mfma_f32_32x32x16_bf16(k0, qA0, sxA, 0, 0, 0);
                sxB = __builtin_amdgcn_mfma_f32_32x32x16_bf16(k0, qB0, sxB, 0, 0, 0);
                const short8 k1 = *(const short8*)(kb0 + 1 * 512 + lane * 8);
                sxA = __builtin_amdgcn_mfma_f32_32x32x16_bf16(k1, qA1, sxA, 0, 0, 0);
                sxB = __builtin_amdgcn_mfma_f32_32x32x16_bf16(k1, qB1, sxB, 0, 0, 0);
                const short8 k2 = *(const short8*)(kb0 + 2 * 512 + lane * 8);
                sxA = __builtin_amdgcn_mfma_f32_32x32x16_bf16(k2, qA2, sxA, 0, 0, 0);
                sxB = __builtin_amdgcn_mfma_f32_32x32x16_bf16(k2, qB2, sxB, 0, 0, 0);
                const short8 k3 = *(const short8*)(kb0 + 3 * 512 + lane * 8);
                sxA = __builtin_amdgcn_mfma_f32_32x32x16_bf16(k3, qA3, sxA, 0, 0, 0);
                sxB = __builtin_amdgcn_mfma_f32_32x32x16_bf16(k3, qB3, sxB, 0, 0, 0);
            }
            __builtin_amdgcn_s_setprio(0);

            // unshifted exact softmax numerators: p = 2^s
            uint32_t pwA[8], pwB[8];
            float cA0 = 0.f, cA1 = 0.f, cB0 = 0.f, cB1 = 0.f;
            #pragma unroll
            for (int q = 0; q < 8; ++q) {
                const float a0 = __builtin_amdgcn_exp2f(sxA[2 * q]);
                const float a1 = __builtin_amdgcn_exp2f(sxA[2 * q + 1]);
                cA0 += a0; cA1 += a1;
                pwA[q] = cvtpk_bf16(a0, a1);
                const float b0 = __builtin_amdgcn_exp2f(sxB[2 * q]);
                const float b1 = __builtin_amdgcn_exp2f(sxB[2 * q + 1]);
                cB0 += b0; cB1 += b1;
                pwB[q] = cvtpk_bf16(b0, b1);
            }
            lA += cA0 + cA1;
            lB += cB0 + cB1;

            union { uint32_t w[4]; short8 v; } pA0u, pA1u, pB0u, pB1u;
            pA0u.w[0] = pwA[0]; pA0u.w[1] = pwA[1]; pA0u.w[2] = pwA[2]; pA0u.w[3] = pwA[3];
            pA1u.w[0] = pwA[4]; pA1u.w[1] = pwA[5]; pA1u.w[2] = pwA[6]; pA1u.w[3] = pwA[7];
            pB0u.w[0] = pwB[0]; pB0u.w[1] = pwB[1]; pB0u.w[2] = pwB[2]; pB0u.w[3] = pwB[3];
            pB1u.w[0] = pwB[4]; pB1u.w[1] = pwB[5]; pB1u.w[2] = pwB[6]; pB1u.w[3] = pwB[7];

            const ushort_t* vb0 = &Vs[buf][cc * 2048];
            __builtin_amdgcn_s_setprio(1);
            {
                const short8 v00 = *(const short8*)(vb0 + 0 * 512 + lane * 8);
                oAA = __builtin_amdgcn_mfma_f32_32x32x16_bf16(v00, pA0u.v, oAA, 0, 0, 0);
                oAB = __builtin_amdgcn_mfma_f32_32x32x16_bf16(v00, pB0u.v, oAB, 0, 0, 0);
                const short8 v01 = *(const short8*)(vb0 + 1 * 512 + lane * 8);
                oBA = __builtin_amdgcn_mfma_f32_32x32x16_bf16(v01, pA0u.v, oBA, 0, 0, 0);
                oBB = __builtin_amdgcn_mfma_f32_32x32x16_bf16(v01, pB0u.v, oBB, 0, 0, 0);
                const short8 v10 = *(const short8*)(vb0 + 2 * 512 + lane * 8);
                oAA = __builtin_amdgcn_mfma_f32_32x32x16_bf16(v10, pA1u.v, oAA, 0, 0, 0);
                oAB = __builtin_amdgcn_mfma_f32_32x32x16_bf16(v10, pB1u.v, oAB, 0, 0, 0);
                const short8 v11 = *(const short8*)(vb0 + 3 * 512 + lane * 8);
                oBA = __builtin_amdgcn_mfma_f32_32x32x16_bf16(v11, pA1u.v, oBA, 0, 0, 0);
                oBB = __builtin_amdgcn_mfma_f32_32x32x16_bf16(v11, pB1u.v, oBB, 0, 0, 0);
            }
            __builtin_amdgcn_s_setprio(0);
        }
        buf ^= 1;
    }

    const float ltA = lA + __shfl_xor(lA, 32);
    const float ltB = lB + __shfl_xor(lB, 32);

    if (ksplit == 1) {
        const float invA = 1.0f / ltA;
        const float invB = 1.0f / ltB;
        ushort_t* orowA = Ot + ((size_t)b * N_ + j0 + l31) * D_;
        ushort_t* orowB = orowA + (size_t)32 * D_;
        #pragma unroll
        for (int q = 0; q < 4; ++q) {
            const int d0 = 8 * q + 4 * h2;
            uint2 u;
            u.x = cvtpk_bf16(oAA[4 * q] * invA,     oAA[4 * q + 1] * invA);
            u.y = cvtpk_bf16(oAA[4 * q + 2] * invA, oAA[4 * q + 3] * invA);
            *(uint2*)&orowA[d0] = u;
            u.x = cvtpk_bf16(oBA[4 * q] * invA,     oBA[4 * q + 1] * invA);
            u.y = cvtpk_bf16(oBA[4 * q + 2] * invA, oBA[4 * q + 3] * invA);
            *(uint2*)&orowA[32 + d0] = u;
            u.x = cvtpk_bf16(oAB[4 * q] * invB,     oAB[4 * q + 1] * invB);
            u.y = cvtpk_bf16(oAB[4 * q + 2] * invB, oAB[4 * q + 3] * invB);
            *(uint2*)&orowB[d0] = u;
            u.x = cvtpk_bf16(oBB[4 * q] * invB,     oBB[4 * q + 1] * invB);
            u.y = cvtpk_bf16(oBB[4 * q + 2] * invB, oBB[4 * q + 3] * invB);
            *(uint2*)&orowB[32 + d0] = u;
        }
    } else {
        ushort_t* orowA = Op + (((size_t)b * ksplit + part) * N_ + j0 + l31) * D_;
        ushort_t* orowB = orowA + (size_t)32 * D_;
        #pragma unroll
        for (int q = 0; q < 4; ++q) {
            const int d0 = 8 * q + 4 * h2;
            uint2 u;
            u.x = cvtpk_bf16(oAA[4 * q],     oAA[4 * q + 1]);
            u.y = cvtpk_bf16(oAA[4 * q + 2], oAA[4 * q + 3]);
            *(uint2*)&orowA[d0] = u;
            u.x = cvtpk_bf16(oBA[4 * q],     oBA[4 * q + 1]);
            u.y = cvtpk_bf16(oBA[4 * q + 2], oBA[4 * q + 3]);
            *(uint2*)&orowA[32 + d0] = u;
            u.x = cvtpk_bf16(oAB[4 * q],     oAB[4 * q + 1]);
            u.y = cvtpk_bf16(oAB[4 * q + 2], oAB[4 * q + 3]);
            *(uint2*)&orowB[d0] = u;
            u.x = cvtpk_bf16(oBB[4 * q],     oBB[4 * q + 1]);
            u.y = cvtpk_bf16(oBB[4 * q + 2], oBB[4 * q + 3]);
            *(uint2*)&orowB[32 + d0] = u;
        }
        if (h2 == 0) {
            const size_t mbase = ((size_t)b * ksplit + part) * N_;
            ml[mbase + j0 + l31]      = ltA;
            ml[mbase + j0 + 32 + l31] = ltB;
        }
    }
}

// -------------------------------------------------------------------------
// Kernel 2b: split-K reduce — plain weighted sum; 8 d per thread.
// -------------------------------------------------------------------------
__global__ __launch_bounds__(256) void reduce_attn(
    const ushort_t* __restrict__ Op, const float* __restrict__ ml,
    ushort_t* __restrict__ Ot, int ksplit)
{
    const int tid = blockIdx.x * 256 + threadIdx.x;   // over B*N*8
    const int d8 = (tid & 7) * 8;
    const int j  = (tid >> 3) & (N_ - 1);
    const int b  = tid >> 15;

    float L = 0.f;
    float v[8] = {0.f, 0.f, 0.f, 0.f, 0.f, 0.f, 0.f, 0.f};
    for (int p = 0; p < ksplit; ++p) {
        const size_t base = ((size_t)b * ksplit + p) * N_ + j;
        L += ml[base];
        uint4 u = *(const uint4*)&Op[base * D_ + d8];
        v[0] += bf2f(u.x & 0xffffu); v[1] += bf2f(u.x >> 16);
        v[2] += bf2f(u.y & 0xffffu); v[3] += bf2f(u.y >> 16);
        v[4] += bf2f(u.z & 0xffffu); v[5] += bf2f(u.z >> 16);
        v[6] += bf2f(u.w & 0xffffu); v[7] += bf2f(u.w >> 16);
    }
    const float inv = 1.0f / L;
    uint4 o;
    o.x = cvtpk_bf16(v[0] * inv, v[1] * inv);
    o.y = cvtpk_bf16(v[2] * inv, v[3] * inv);
    o.z = cvtpk_bf16(v[4] * inv, v[5] * inv);
    o.w = cvtpk_bf16(v[6] * inv, v[7] * inv);
    *(uint4*)&Ot[((size_t)b * N_ + j) * D_ + d8] = o;
}

// -------------------------------------------------------------------------
// Kernel 3: output projection + residual (verified since round 0).
// -------------------------------------------------------------------------
__global__ __launch_bounds__(256) void outproj(
    const ushort_t* __restrict__ Ot, const float* __restrict__ wv,
    const float* __restrict__ bv, const float* __restrict__ gamma,
    const float* __restrict__ x, float* __restrict__ y)
{
    const int b    = blockIdx.z;
    const int wave = threadIdx.x >> 6;
    const int lane = threadIdx.x & 63;
    const int g    = lane >> 4;
    const int r    = lane & 15;
    const int co0  = blockIdx.y * 64 + wave * 16;
    const int n0   = blockIdx.x * 64;

    const float* wrow = wv + (size_t)(co0 + r) * D_ + 8 * g;
    short8 a0, a1;
    #pragma unroll
    for (int j = 0; j < 8; ++j) {
        a0[j] = (short)f2bf(wrow[j]);
        a1[j] = (short)f2bf(wrow[32 + j]);
    }

    f32x4 acc[4];
    #pragma unroll
    for (int t = 0; t < 4; ++t) acc[t] = (f32x4){0.f, 0.f, 0.f, 0.f};

    #pragma unroll
    for (int t = 0; t < 4; ++t) {
        const ushort_t* op = Ot + ((size_t)b * N_ + n0 + 16 * t + r) * D_ + 8 * g;
        short8 b0 = *(const short8*)op;
        short8 b1 = *(const short8*)(op + 32);
        acc[t] = __builtin_amdgcn_mfma_f32_16x16x32_bf16(a0, b0, acc[t], 0, 0, 0);
        acc[t] = __builtin_amdgcn_mfma_f32_16x16x32_bf16(a1, b1, acc[t], 0, 0, 0);
    }

    const float gm = *gamma;
    #pragma unroll
    for (int t = 0; t < 4; ++t) {
        #pragma unroll
        for (int j = 0; j < 4; ++j) {
            const int co = co0 + 4 * g + j;
            const int n  = n0 + 16 * t + r;
            const size_t idx = ((size_t)b * C_ + co) * N_ + n;
            y[idx] = gm * (acc[t][j] + bv[co]) + x[idx];
        }
    }
}

// -------------------------------------------------------------------------
extern "C" void kernel_launch(void* const* d_in, const int* in_sizes, int n_in,
                              void* d_out, int out_size, void* d_ws, size_t ws_size,
                              hipStream_t stream) {
    const float* x     = (const float*)d_in[0];
    const float* wf    = (const float*)d_in[1];
    const float* bf    = (const float*)d_in[2];
    const float* wg    = (const float*)d_in[3];
    const float* bg    = (const float*)d_in[4];
    const float* wh    = (const float*)d_in[5];
    const float* bh    = (const float*)d_in[6];
    const float* wv    = (const float*)d_in[7];
    const float* bv    = (const float*)d_in[8];
    const float* gamma = (const float*)d_in[9];
    float* y = (float*)d_out;

    const size_t plane = (size_t)B_ * N_ * D_;   // 1M elements
    ushort_t* Ftf = (ushort_t*)d_ws;             // pre-swizzled K fragments
    ushort_t* Gt  = Ftf + plane;                 // Q rows
    ushort_t* Vtf = Gt + plane;                  // pre-swizzled V fragments
    ushort_t* Ot  = Vtf + plane;                 // attention output rows
    ushort_t* Op  = Ot + plane;                  // split-K partials (bf16)

    int KS = 8;
    while (KS > 1) {
        const size_t need = 4 * plane * 2 + (size_t)KS * plane * 2
                          + (size_t)B_ * KS * N_ * sizeof(float);
        if (need <= ws_size) break;
        KS >>= 1;
    }
    float* ml = (float*)(Op + (size_t)KS * plane);

    proj_fgh<<<dim3(N_ / 64, B_), 512, 0, stream>>>(
        x, wf, bf, wg, bg, wh, bh, Ftf, Gt, Vtf);
    attn<<<dim3(N_ / 256, KS, B_), 256, 0, stream>>>(
        Ftf, Gt, Vtf, Ot, Op, ml, KS);
    if (KS > 1)
        reduce_attn<<<(B_ * N_ * 8) / 256, 256, 0, stream>>>(Op, ml, Ot, KS);
    outproj<<<dim3(N_ / 64, C_ / 64, B_), 256, 0, stream>>>(Ot, wv, bv, gamma, x, y);
}